// Round 9
// baseline (446.099 us; speedup 1.0000x reference)
//
#include <hip/hip_runtime.h>
#include <hip/hip_bf16.h>

typedef __hip_bfloat16 bf16;
typedef __attribute__((ext_vector_type(8))) short short8;
typedef __attribute__((ext_vector_type(4))) float f32x4;
typedef __attribute__((ext_vector_type(16))) float f32x16;

#define MFMA_BF16(a,b,c) __builtin_amdgcn_mfma_f32_16x16x32_bf16(a,b,c,0,0,0)
#define MFMA32(a,b,c)    __builtin_amdgcn_mfma_f32_32x32x16_bf16(a,b,c,0,0,0)

// single-instruction exp2 (lane-local VOP1); score scale folds log2(e)
__device__ __forceinline__ float exp2_hw(float x){
  float r; asm("v_exp_f32 %0, %1" : "=v"(r) : "v"(x)); return r;
}
#define EXPFN(x) exp2_hw(x)
#define QSCALE 0.1803368801111204f   /* 0.125 * log2(e) */

__device__ __forceinline__ unsigned short bfbits(float f){
  bf16 h = __float2bfloat16(f);
  return __builtin_bit_cast(unsigned short, h);
}
__device__ __forceinline__ unsigned packbf(float a, float b){
  return (unsigned)bfbits(a) | ((unsigned)bfbits(b) << 16);
}

// async global->LDS 16B. LDS dest must be wave-uniform base + lane*16 (linear).
__device__ __forceinline__ void glds16(const void* g, void* l){
  __builtin_amdgcn_global_load_lds(
      (const __attribute__((address_space(1))) unsigned int*)(size_t)g,
      (__attribute__((address_space(3))) unsigned int*)l, 16, 0, 0);
}

// ---------------- fused x fp32->bf16 convert + mean partial (stage 1) ----------------
__global__ __launch_bounds__(256)
void xconv_mean(const float* __restrict__ x, bf16* __restrict__ xb, float* __restrict__ part){
  int b = blockIdx.x, ch = blockIdx.y, t = threadIdx.x;
  size_t base = ((size_t)b*1024 + (size_t)ch*64)*512;
  const float2* xp = (const float2*)(x + base);
  unsigned* op = (unsigned*)(xb + base);
  float s0 = 0.f, s1 = 0.f;
#pragma unroll 4
  for (int s = 0; s < 64; ++s){
    float2 v = xp[s*256 + t];
    s0 += v.x; s1 += v.y;
    op[s*256 + t] = packbf(v.x, v.y);
  }
  float* pp = part + ((size_t)b*16 + ch)*512;
  pp[2*t]   = s0;
  pp[2*t+1] = s1;
}

// ---------------- fused mean-final + router MLP + argmax (fp32, same op order) ----------------
__global__ __launch_bounds__(256)
void router_fused(const float* __restrict__ part,
                  const float* __restrict__ w1, const float* __restrict__ b1,
                  const float* __restrict__ w2, const float* __restrict__ b2,
                  int* __restrict__ sel){
  int b = blockIdx.x, t = threadIdx.x;
  __shared__ float rs[512];
  __shared__ float h[128];
  __shared__ float lg[3];
  for (int dd = t; dd < 512; dd += 256){
    float a = 0.f;
    for (int c = 0; c < 16; ++c) a += part[((size_t)b*16 + c)*512 + dd];
    rs[dd] = a * (1.f/1024.f);
  }
  __syncthreads();
  if (t < 128){
    float acc = b1[t];
    for (int d = 0; d < 512; ++d) acc += rs[d]*w1[(size_t)d*128 + t];
    h[t] = fmaxf(acc, 0.f);
  }
  __syncthreads();
  if (t < 3){
    float a = b2[t];
    for (int j = 0; j < 128; ++j) a += h[j]*w2[j*3 + t];
    lg[t] = a;
  }
  __syncthreads();
  if (t == 0){
    int best = 0; float bv = lg[0];
    if (lg[1] > bv){ bv = lg[1]; best = 1; }
    if (lg[2] > bv){ bv = lg[2]; best = 2; }
    sel[b] = best;
  }
}

// ---------------- weight transpose-convert (generic tile body) ----------------
__device__ __forceinline__ void wconv_tile(const float* __restrict__ W, int N,
                                           bf16* __restrict__ dst, int n0, int k0){
  __shared__ float tile[64][65];
  int t = threadIdx.x;
#pragma unroll
  for (int j=0;j<16;++j){
    int ee = j*256+t; int r = ee>>6, c = ee&63;
    tile[r][c] = W[(size_t)(k0+r)*N + n0+c];
  }
  __syncthreads();
#pragma unroll
  for (int j=0;j<16;++j){
    int ee = j*256+t; int n = ee>>6, kk = ee&63;
    dst[(size_t)(n0+n)*512 + k0+kk] = __float2bfloat16(tile[kk][n]);
  }
}

// 9 segments: z 0..2 Q experts, 3..5 K experts, 6..8 V experts (packed per-expert rows)
__global__ __launch_bounds__(256)
void wconv_qkv(const float* q0,const float* q1,const float* q2,
               const float* k0p,const float* k1p,const float* k2p,
               const float* v0p,const float* v1p,const float* v2p,
               bf16* wqt, bf16* wkt, bf16* wvt){
  int zz = blockIdx.z;
  const float* W; int N; bf16* dst;
  if (zz < 3){ W = zz==0?q0:(zz==1?q1:q2); N = 512; dst = wqt + (size_t)zz*512*512; }
  else if (zz < 6){ int e=zz-3; W = e==0?k0p:(e==1?k1p:k2p); N = e==0?512:(e==1?256:64);
                    dst = wkt + (size_t)(e==0?0:(e==1?512:768))*512; }
  else { int e=zz-6; W = e==0?v0p:(e==1?v1p:v2p); N = e==0?512:(e==1?256:64);
         dst = wvt + (size_t)(e==0?0:(e==1?512:768))*512; }
  int n0 = blockIdx.y*64; if (n0 >= N) return;
  wconv_tile(W, N, dst, n0, blockIdx.x*64);
}

// 3 segments for O weights (runs after Q-GEMM; reuses Q weight buffer)
__global__ __launch_bounds__(256)
void wconv_o(const float* o0,const float* o1,const float* o2, bf16* wot){
  int e = blockIdx.z;
  const float* W = e==0?o0:(e==1?o1:o2);
  wconv_tile(W, 512, wot + (size_t)e*512*512, blockIdx.y*64, blockIdx.x*64);
}

// ---------------- MFMA GEMM (double-buffered 2-phase): C[b] = A[b] @ W(sel[b]) ----------------
// Wt: transposed weights [N][512] bf16. Tile 128m x 128n x 64k; STAGE(next) issued before MFMA;
// one barrier per K-step (attn-proven pattern). LDS 64KB -> 2 blocks/CU.
// OUTMODE 0: bf16 row-major (scaled by oscale); 2: f32 row-major.
template<int OUTMODE>
__global__ __launch_bounds__(256)
void gemm_mfma(const bf16* __restrict__ A,
               const bf16* __restrict__ Wt0, const bf16* __restrict__ Wt1, const bf16* __restrict__ Wt2,
               const int* __restrict__ sel, float oscale,
               void* __restrict__ outp){
  int b = blockIdx.z;
  int se = sel[b];
  const bf16* W = se==0?Wt0:(se==1?Wt1:Wt2);
  int nb = blockIdx.y*128;
  int mb = blockIdx.x*128;
  __shared__ __align__(16) bf16 As[2][128*64];
  __shared__ __align__(16) bf16 Bs[2][128*64];
  int t = threadIdx.x, lane = t&63, w = t>>6, gg = lane>>4, cl = lane&15;
  f32x4 acc[2][8] = {};
  const bf16* Ab = A + ((size_t)b*1024 + mb)*512;
  const bf16* Wb = W + (size_t)nb*512;

#define GSTAGE(CUR, K0) { \
  _Pragma("unroll") for (int j=0;j<4;++j){ \
    int o = (j*256+t)*16; int r = o>>7; int gs = ((o>>4)&7) ^ (r&7); \
    glds16(Ab + (size_t)r*512 + (K0) + gs*8, (char*)As[CUR] + o); } \
  _Pragma("unroll") for (int j=0;j<4;++j){ \
    int o = (j*256+t)*16; int r = o>>7; int gs = ((o>>4)&7) ^ (r&7); \
    glds16(Wb + (size_t)r*512 + (K0) + gs*8, (char*)Bs[CUR] + o); } \
  }

  GSTAGE(0, 0)
  __syncthreads();
  int cur = 0;
  for (int k0 = 0; k0 < 512; k0 += 64){
    if (k0 + 64 < 512) GSTAGE(cur^1, k0+64)

    short8 af[2][2];
#pragma unroll
    for (int mf=0;mf<2;++mf)
#pragma unroll
      for (int ks=0;ks<2;++ks){
        int r = w*32 + mf*16 + cl;
        int off = (ks*64 + gg*16) ^ ((r&7)<<4);
        af[mf][ks] = *(const short8*)((const char*)As[cur] + r*128 + off);
      }
#pragma unroll
    for (int nf=0;nf<8;++nf){
      int r = nf*16 + cl;
      int rs = (r&7)<<4;
      short8 b0 = *(const short8*)((const char*)Bs[cur] + r*128 + ((gg*16) ^ rs));
      short8 b1 = *(const short8*)((const char*)Bs[cur] + r*128 + ((64 + gg*16) ^ rs));
      acc[0][nf] = MFMA_BF16(af[0][0], b0, acc[0][nf]);
      acc[0][nf] = MFMA_BF16(af[0][1], b1, acc[0][nf]);
      acc[1][nf] = MFMA_BF16(af[1][0], b0, acc[1][nf]);
      acc[1][nf] = MFMA_BF16(af[1][1], b1, acc[1][nf]);
    }
    __syncthreads();
    cur ^= 1;
  }
#undef GSTAGE

#pragma unroll
  for (int mf=0;mf<2;++mf)
#pragma unroll
    for (int nf=0;nf<8;++nf){
      int row = mb + w*32 + mf*16 + gg*4;
      int col = nb + nf*16 + cl;
      if (OUTMODE==0){
        bf16* C = (bf16*)outp;
#pragma unroll
        for (int i=0;i<4;++i)
          C[((size_t)b*1024 + row+i)*512 + col] = __float2bfloat16(acc[mf][nf][i]*oscale);
      } else {
        float* C = (float*)outp;
#pragma unroll
        for (int i=0;i<4;++i)
          C[((size_t)b*1024 + row+i)*512 + col] = acc[mf][nf][i];
      }
    }
}

// ---------------- fused K+V projection (double-buffered): K row-major + V transposed ----------------
__global__ __launch_bounds__(256)
void gemm_kv(const bf16* __restrict__ A,
             const bf16* __restrict__ wkt, const bf16* __restrict__ wvt,
             const int* __restrict__ sel,
             bf16* __restrict__ Kb, bf16* __restrict__ Vt){
  int b = blockIdx.z;
  int se = sel[b];
  int NK = se==0?512:(se==1?256:64);
  int nb = blockIdx.y*64;
  if (nb >= NK) return;
  int roff = se==0?0:(se==1?512:768);
  int mb = blockIdx.x*128;
  __shared__ __align__(16) bf16 As[2][128*64];
  __shared__ __align__(16) bf16 Bk[2][64*64];
  __shared__ __align__(16) bf16 Bv[2][64*64];
  int t = threadIdx.x, lane = t&63, w = t>>6, gg = lane>>4, cl = lane&15;
  f32x4 accK[2][4] = {}, accV[2][4] = {};
  const bf16* Ab = A + ((size_t)b*1024 + mb)*512;
  const bf16* Wk = wkt + (size_t)(roff+nb)*512;
  const bf16* Wv = wvt + (size_t)(roff+nb)*512;

#define KVSTAGE(CUR, K0) { \
  _Pragma("unroll") for (int j=0;j<4;++j){ \
    int o = (j*256+t)*16; int r = o>>7; int gs = ((o>>4)&7) ^ (r&7); \
    glds16(Ab + (size_t)r*512 + (K0) + gs*8, (char*)As[CUR] + o); } \
  _Pragma("unroll") for (int j=0;j<2;++j){ \
    int o = (j*256+t)*16; int r = o>>7; int gs = ((o>>4)&7) ^ (r&7); \
    glds16(Wk + (size_t)r*512 + (K0) + gs*8, (char*)Bk[CUR] + o); \
    glds16(Wv + (size_t)r*512 + (K0) + gs*8, (char*)Bv[CUR] + o); } \
  }

  KVSTAGE(0, 0)
  __syncthreads();
  int cur = 0;
  for (int k0 = 0; k0 < 512; k0 += 64){
    if (k0 + 64 < 512) KVSTAGE(cur^1, k0+64)

    short8 af[2][2];
#pragma unroll
    for (int mf=0;mf<2;++mf)
#pragma unroll
      for (int ks=0;ks<2;++ks){
        int r = w*32 + mf*16 + cl;
        int off = (ks*64 + gg*16) ^ ((r&7)<<4);
        af[mf][ks] = *(const short8*)((const char*)As[cur] + r*128 + off);
      }
#pragma unroll
    for (int nf=0;nf<4;++nf){
      int r = nf*16 + cl;
      int rs = (r&7)<<4;
      short8 bk0 = *(const short8*)((const char*)Bk[cur] + r*128 + ((gg*16) ^ rs));
      short8 bk1 = *(const short8*)((const char*)Bk[cur] + r*128 + ((64 + gg*16) ^ rs));
      short8 bv0 = *(const short8*)((const char*)Bv[cur] + r*128 + ((gg*16) ^ rs));
      short8 bv1 = *(const short8*)((const char*)Bv[cur] + r*128 + ((64 + gg*16) ^ rs));
      accK[0][nf] = MFMA_BF16(af[0][0], bk0, accK[0][nf]);
      accK[0][nf] = MFMA_BF16(af[0][1], bk1, accK[0][nf]);
      accK[1][nf] = MFMA_BF16(af[1][0], bk0, accK[1][nf]);
      accK[1][nf] = MFMA_BF16(af[1][1], bk1, accK[1][nf]);
      accV[0][nf] = MFMA_BF16(af[0][0], bv0, accV[0][nf]);
      accV[0][nf] = MFMA_BF16(af[0][1], bv1, accV[0][nf]);
      accV[1][nf] = MFMA_BF16(af[1][0], bv0, accV[1][nf]);
      accV[1][nf] = MFMA_BF16(af[1][1], bv1, accV[1][nf]);
    }
    __syncthreads();
    cur ^= 1;
  }
#undef KVSTAGE

#pragma unroll
  for (int mf=0;mf<2;++mf)
#pragma unroll
    for (int nf=0;nf<4;++nf){
      int row = mb + w*32 + mf*16 + gg*4;
      int col = nb + nf*16 + cl;
#pragma unroll
      for (int i=0;i<4;++i)
        Kb[((size_t)b*1024 + row+i)*512 + col] = __float2bfloat16(accK[mf][nf][i]);
      union { unsigned short u[4]; uint2 v; } pk;
#pragma unroll
      for (int i=0;i<4;++i) pk.u[i] = bfbits(accV[mf][nf][i]);
      *(uint2*)(Vt + ((size_t)b*512 + col)*1024 + row) = pk.v;
    }
}

// ---------------- MFMA flash attention (unchanged from R8) ----------------
__global__ __launch_bounds__(256, 4)
void attn_mfma(const bf16* __restrict__ Q, const bf16* __restrict__ K,
               const bf16* __restrict__ Vt, const int* __restrict__ sel,
               bf16* __restrict__ AO){
  int b = blockIdx.z, h = blockIdx.y, q0 = blockIdx.x*128;
  int se = sel[b];
  int nkv = se==0?8:(se==1?4:1);
  int kvh = h/(8/nkv);
  __shared__ __align__(16) bf16 Ks[2][64*64];
  __shared__ __align__(16) bf16 Vs[2][64*64];
  int t = threadIdx.x, l = t&63, w = t>>6, cl = l&31, hi = l>>5;
  const bf16* Kb = K + (size_t)b*1024*512 + (size_t)kvh*64;
  const bf16* Vb = Vt + ((size_t)b*512 + (size_t)kvh*64)*1024;
  const bf16* Qg = Q + ((size_t)b*1024 + q0 + w*32 + cl)*512 + h*64;

  short8 qf0 = *(const short8*)(Qg + hi*8);
  short8 qf1 = *(const short8*)(Qg + 16 + hi*8);
  short8 qf2 = *(const short8*)(Qg + 32 + hi*8);
  short8 qf3 = *(const short8*)(Qg + 48 + hi*8);

  f32x16 accO0 = {}, accO1 = {};
  float lrow = 0.f;
  int swz = (cl&7)<<4;

#define STAGE(CUR, S0) { \
  _Pragma("unroll") for (int j=0;j<2;++j){ \
    int o = (j*256+t)*16; int r = o>>7; int gs = ((o>>4)&7)^(r&7); \
    glds16(Kb + (size_t)((S0)+r)*512 + gs*8, (char*)Ks[CUR] + o); \
    glds16(Vb + (size_t)r*1024 + (S0) + gs*8, (char*)Vs[CUR] + o); \
  } }

  STAGE(0, 0)
  __syncthreads();
  int cur = 0;
  for (int kt=0; kt<16; ++kt){
    if (kt<15) STAGE(cur^1, (kt+1)*64)

    const char* Kt_ = (const char*)Ks[cur];
    const char* Vt_ = (const char*)Vs[cur];

    f32x16 sc0 = {}, sc1 = {};
    __builtin_amdgcn_s_setprio(1);
#pragma unroll
    for (int ks=0;ks<4;++ks){
      int off = (ks*32 + hi*16) ^ swz;
      short8 kf0 = *(const short8*)(Kt_ + (size_t)cl*128 + off);
      short8 kf1 = *(const short8*)(Kt_ + (size_t)(32+cl)*128 + off);
      short8 qq = ks==0?qf0:(ks==1?qf1:(ks==2?qf2:qf3));
      sc0 = MFMA32(kf0, qq, sc0);
      sc1 = MFMA32(kf1, qq, sc1);
    }
    __builtin_amdgcn_s_setprio(0);

    float ts0=0.f, ts1=0.f, ts2=0.f, ts3=0.f;
#pragma unroll
    for (int r=0;r<16;r+=2){
      float a0 = EXPFN(sc0[r]);   float a1 = EXPFN(sc0[r+1]);
      float a2 = EXPFN(sc1[r]);   float a3 = EXPFN(sc1[r+1]);
      sc0[r]=a0; sc0[r+1]=a1; sc1[r]=a2; sc1[r+1]=a3;
      ts0+=a0; ts1+=a1; ts2+=a2; ts3+=a3;
    }
    lrow += (ts0+ts1)+(ts2+ts3);

    unsigned pA0[4],pB0[4],pA1[4],pB1[4];
#pragma unroll
    for (int m=0;m<4;++m){
      pA0[m]=packbf(sc0[4*m+0],sc0[4*m+1]); pB0[m]=packbf(sc0[4*m+2],sc0[4*m+3]);
      pA1[m]=packbf(sc1[4*m+0],sc1[4*m+1]); pB1[m]=packbf(sc1[4*m+2],sc1[4*m+3]);
    }
    unsigned rA0[2],rB0[2],rA1[2],rB1[2];
#pragma unroll
    for (int f=0;f<2;++f){
      rA0[f] = __shfl_xor(hi ? pA0[2*f] : pA0[2*f+1], 32);
      rB0[f] = __shfl_xor(hi ? pB0[2*f] : pB0[2*f+1], 32);
      rA1[f] = __shfl_xor(hi ? pA1[2*f] : pA1[2*f+1], 32);
      rB1[f] = __shfl_xor(hi ? pB1[2*f] : pB1[2*f+1], 32);
    }
    short8 pF[4];
#pragma unroll
    for (int f=0;f<2;++f){
      uint4 u;
      u.x = hi ? rA0[f]     : pA0[2*f];
      u.y = hi ? rB0[f]     : pB0[2*f];
      u.z = hi ? pA0[2*f+1] : rA0[f];
      u.w = hi ? pB0[2*f+1] : rB0[f];
      pF[f] = __builtin_bit_cast(short8, u);
      uint4 v;
      v.x = hi ? rA1[f]     : pA1[2*f];
      v.y = hi ? rB1[f]     : pB1[2*f];
      v.z = hi ? pA1[2*f+1] : rA1[f];
      v.w = hi ? pB1[2*f+1] : rB1[f];
      pF[2+f] = __builtin_bit_cast(short8, v);
    }

    __builtin_amdgcn_s_setprio(1);
#pragma unroll
    for (int ks2=0;ks2<4;++ks2){
      int off = (ks2*32 + hi*16) ^ swz;
      short8 vf0 = *(const short8*)(Vt_ + (size_t)cl*128 + off);
      short8 vf1 = *(const short8*)(Vt_ + (size_t)(32+cl)*128 + off);
      accO0 = MFMA32(vf0, pF[ks2], accO0);
      accO1 = MFMA32(vf1, pF[ks2], accO1);
    }
    __builtin_amdgcn_s_setprio(0);
    __syncthreads();
    cur ^= 1;
  }
#undef STAGE

  float lfull = lrow + __shfl_xor(lrow, 32);
  float inv = 1.f/lfull;
  int row = q0 + w*32 + cl;
  bf16* Ao = AO + ((size_t)b*1024 + row)*512 + h*64;
#pragma unroll
  for (int u=0;u<4;++u){
    union{ unsigned short s[4]; uint2 v; } P0, P1;
#pragma unroll
    for (int j2=0;j2<4;++j2){
      P0.s[j2] = bfbits(accO0[4*u+j2]*inv);
      P1.s[j2] = bfbits(accO1[4*u+j2]*inv);
    }
    *(uint2*)(Ao + 8*u + 4*hi) = P0.v;
    *(uint2*)(Ao + 32 + 8*u + 4*hi) = P1.v;
  }
}

extern "C" void kernel_launch(void* const* d_in, const int* in_sizes, int n_in,
                              void* d_out, int out_size, void* d_ws, size_t ws_size,
                              hipStream_t stream){
  const float* x    = (const float*)d_in[0];
  const float* r_w1 = (const float*)d_in[1];
  const float* r_b1 = (const float*)d_in[2];
  const float* r_w2 = (const float*)d_in[3];
  const float* r_b2 = (const float*)d_in[4];
  const float* wq[3] = {(const float*)d_in[5], (const float*)d_in[9],  (const float*)d_in[13]};
  const float* wk[3] = {(const float*)d_in[6], (const float*)d_in[10], (const float*)d_in[14]};
  const float* wv[3] = {(const float*)d_in[7], (const float*)d_in[11], (const float*)d_in[15]};
  const float* wo[3] = {(const float*)d_in[8], (const float*)d_in[12], (const float*)d_in[16]};

  // ws layout (4MiB header + 4*64MiB = 260MiB, proven footprint):
  char* ws = (char*)d_ws;
  int*   sel      = (int*)ws;
  float* partials = (float*)(ws + 4096);
  bf16*  wqt      = (bf16*)(ws + 4096);
  bf16*  wkt      = (bf16*)(ws + 4096 + 1572864);
  bf16*  wvt      = (bf16*)(ws + 4096 + 1572864 + 851968);
  bf16*  wot      = wqt;                         // O weights reuse Q region (after Q-GEMM)
  const size_t NE = (size_t)64*1024*512;
  bf16* xb = (bf16*)(ws + ((size_t)4<<20));
  bf16* Qb = xb + NE;
  bf16* Kb = Qb + NE;
  bf16* Vt = Kb + NE;
  bf16* AO = xb;                                 // alias: xb dead before attention writes

  xconv_mean<<<dim3(64,16), 256, 0, stream>>>(x, xb, partials);
  router_fused<<<64, 256, 0, stream>>>(partials, r_w1, r_b1, r_w2, r_b2, sel);

  wconv_qkv<<<dim3(8,8,9), 256, 0, stream>>>(wq[0],wq[1],wq[2], wk[0],wk[1],wk[2],
                                             wv[0],wv[1],wv[2], wqt, wkt, wvt);

  // Q projection (scores scale folded into Q), 128x128 dbuf tile
  gemm_mfma<0><<<dim3(8,4,64), 256, 0, stream>>>(
      xb, wqt, wqt + (size_t)512*512, wqt + (size_t)2*512*512, sel, (float)QSCALE, Qb);

  // fused K+V projection (shared A-tiles, dbuf), 128x64 tile
  gemm_kv<<<dim3(8,8,64), 256, 0, stream>>>(xb, wkt, wvt, sel, Kb, Vt);

  // O weight transpose into the (now dead) Q weight buffer
  wconv_o<<<dim3(8,8,3), 256, 0, stream>>>(wo[0],wo[1],wo[2], wot);

  attn_mfma<<<dim3(8,8,64), 256, 0, stream>>>(Qb, Kb, Vt, sel, AO);

  // O projection (fp32 out), 128x128 dbuf tile
  gemm_mfma<2><<<dim3(8,4,64), 256, 0, stream>>>(
      AO, wot, wot + (size_t)512*512, wot + (size_t)2*512*512, sel, 1.0f, (float*)d_out);
}

// Round 11
// 408.493 us; speedup vs baseline: 1.0921x; 1.0921x over previous
//
#include <hip/hip_runtime.h>
#include <hip/hip_bf16.h>

typedef __hip_bfloat16 bf16;
typedef __attribute__((ext_vector_type(8))) short short8;
typedef __attribute__((ext_vector_type(4))) float f32x4;
typedef __attribute__((ext_vector_type(16))) float f32x16;

#define MFMA_BF16(a,b,c) __builtin_amdgcn_mfma_f32_16x16x32_bf16(a,b,c,0,0,0)
#define MFMA32(a,b,c)    __builtin_amdgcn_mfma_f32_32x32x16_bf16(a,b,c,0,0,0)

// single-instruction exp2 (lane-local VOP1); score scale folds log2(e)
__device__ __forceinline__ float exp2_hw(float x){
  float r; asm("v_exp_f32 %0, %1" : "=v"(r) : "v"(x)); return r;
}
#define EXPFN(x) exp2_hw(x)
#define QSCALE 0.1803368801111204f   /* 0.125 * log2(e) */

__device__ __forceinline__ unsigned short bfbits(float f){
  bf16 h = __float2bfloat16(f);
  return __builtin_bit_cast(unsigned short, h);
}
__device__ __forceinline__ unsigned packbf(float a, float b){
  return (unsigned)bfbits(a) | ((unsigned)bfbits(b) << 16);
}

// async global->LDS 16B. LDS dest must be wave-uniform base + lane*16 (linear).
__device__ __forceinline__ void glds16(const void* g, void* l){
  __builtin_amdgcn_global_load_lds(
      (const __attribute__((address_space(1))) unsigned int*)(size_t)g,
      (__attribute__((address_space(3))) unsigned int*)l, 16, 0, 0);
}

// ---------------- fused x fp32->bf16 convert + mean partial (stage 1) ----------------
__global__ __launch_bounds__(256)
void xconv_mean(const float* __restrict__ x, bf16* __restrict__ xb, float* __restrict__ part){
  int b = blockIdx.x, ch = blockIdx.y, t = threadIdx.x;
  size_t base = ((size_t)b*1024 + (size_t)ch*64)*512;
  const float2* xp = (const float2*)(x + base);
  unsigned* op = (unsigned*)(xb + base);
  float s0 = 0.f, s1 = 0.f;
#pragma unroll 4
  for (int s = 0; s < 64; ++s){
    float2 v = xp[s*256 + t];
    s0 += v.x; s1 += v.y;
    op[s*256 + t] = packbf(v.x, v.y);
  }
  float* pp = part + ((size_t)b*16 + ch)*512;
  pp[2*t]   = s0;
  pp[2*t+1] = s1;
}

// ---------------- fused mean-final + router MLP + argmax (fp32, same op order) ----------------
__global__ __launch_bounds__(256)
void router_fused(const float* __restrict__ part,
                  const float* __restrict__ w1, const float* __restrict__ b1,
                  const float* __restrict__ w2, const float* __restrict__ b2,
                  int* __restrict__ sel){
  int b = blockIdx.x, t = threadIdx.x;
  __shared__ float rs[512];
  __shared__ float h[128];
  __shared__ float lg[3];
  for (int dd = t; dd < 512; dd += 256){
    float a = 0.f;
    for (int c = 0; c < 16; ++c) a += part[((size_t)b*16 + c)*512 + dd];
    rs[dd] = a * (1.f/1024.f);
  }
  __syncthreads();
  if (t < 128){
    float acc = b1[t];
    for (int d = 0; d < 512; ++d) acc += rs[d]*w1[(size_t)d*128 + t];
    h[t] = fmaxf(acc, 0.f);
  }
  __syncthreads();
  if (t < 3){
    float a = b2[t];
    for (int j = 0; j < 128; ++j) a += h[j]*w2[j*3 + t];
    lg[t] = a;
  }
  __syncthreads();
  if (t == 0){
    int best = 0; float bv = lg[0];
    if (lg[1] > bv){ bv = lg[1]; best = 1; }
    if (lg[2] > bv){ bv = lg[2]; best = 2; }
    sel[b] = best;
  }
}

// ---------------- weight transpose-convert (generic tile body) ----------------
__device__ __forceinline__ void wconv_tile(const float* __restrict__ W, int N,
                                           bf16* __restrict__ dst, int n0, int k0){
  __shared__ float tile[64][65];
  int t = threadIdx.x;
#pragma unroll
  for (int j=0;j<16;++j){
    int ee = j*256+t; int r = ee>>6, c = ee&63;
    tile[r][c] = W[(size_t)(k0+r)*N + n0+c];
  }
  __syncthreads();
#pragma unroll
  for (int j=0;j<16;++j){
    int ee = j*256+t; int n = ee>>6, kk = ee&63;
    dst[(size_t)(n0+n)*512 + k0+kk] = __float2bfloat16(tile[kk][n]);
  }
}

// 9 segments: z 0..2 Q experts, 3..5 K experts, 6..8 V experts (packed per-expert rows)
__global__ __launch_bounds__(256)
void wconv_qkv(const float* q0,const float* q1,const float* q2,
               const float* k0p,const float* k1p,const float* k2p,
               const float* v0p,const float* v1p,const float* v2p,
               bf16* wqt, bf16* wkt, bf16* wvt){
  int zz = blockIdx.z;
  const float* W; int N; bf16* dst;
  if (zz < 3){ W = zz==0?q0:(zz==1?q1:q2); N = 512; dst = wqt + (size_t)zz*512*512; }
  else if (zz < 6){ int e=zz-3; W = e==0?k0p:(e==1?k1p:k2p); N = e==0?512:(e==1?256:64);
                    dst = wkt + (size_t)(e==0?0:(e==1?512:768))*512; }
  else { int e=zz-6; W = e==0?v0p:(e==1?v1p:v2p); N = e==0?512:(e==1?256:64);
         dst = wvt + (size_t)(e==0?0:(e==1?512:768))*512; }
  int n0 = blockIdx.y*64; if (n0 >= N) return;
  wconv_tile(W, N, dst, n0, blockIdx.x*64);
}

// 3 segments for O weights (runs after Q-GEMM; reuses Q weight buffer)
__global__ __launch_bounds__(256)
void wconv_o(const float* o0,const float* o1,const float* o2, bf16* wot){
  int e = blockIdx.z;
  const float* W = e==0?o0:(e==1?o1:o2);
  wconv_tile(W, 512, wot + (size_t)e*512*512, blockIdx.y*64, blockIdx.x*64);
}

// ---------------- MFMA GEMM (R8 single-buffered — proven): C[b] = A[b] @ W(sel[b]) ----------------
// Wt: transposed weights [N][512] bf16. Tile 128m x BNn x 64k.
// OUTMODE 0: bf16 row-major (scaled by oscale); 2: f32 row-major.
template<int OUTMODE, int BN>
__global__ __launch_bounds__(256)
void gemm_mfma(const bf16* __restrict__ A,
               const bf16* __restrict__ Wt0, const bf16* __restrict__ Wt1, const bf16* __restrict__ Wt2,
               int N0, int N1, int N2,
               const int* __restrict__ sel, float oscale,
               void* __restrict__ outp){
  int b = blockIdx.z;
  int se = sel[b];
  const bf16* W = se==0?Wt0:(se==1?Wt1:Wt2);
  int N = se==0?N0:(se==1?N1:N2);
  int nb = blockIdx.y*BN;
  if (nb >= N) return;
  int mb = blockIdx.x*128;
  __shared__ __align__(16) bf16 As[128*64];
  __shared__ __align__(16) bf16 Bs[BN*64];
  int t = threadIdx.x, lane = t&63, w = t>>6, gg = lane>>4, cl = lane&15;
  f32x4 acc[2][BN/16] = {};
  const bf16* Ab = A + ((size_t)b*1024 + mb)*512;
  const bf16* Wb = W + (size_t)nb*512;

  for (int k0 = 0; k0 < 512; k0 += 64){
#pragma unroll
    for (int j=0;j<4;++j){
      int o = (j*256+t)*16;
      int r = o>>7;
      int gs = ((o>>4)&7) ^ (r&7);
      glds16(Ab + (size_t)r*512 + k0 + gs*8, (char*)As + o);
    }
#pragma unroll
    for (int j=0;j<BN/32;++j){
      int o = (j*256+t)*16;
      int r = o>>7;
      int gs = ((o>>4)&7) ^ (r&7);
      glds16(Wb + (size_t)r*512 + k0 + gs*8, (char*)Bs + o);
    }
    __syncthreads();

    short8 af[2][2];
#pragma unroll
    for (int mf=0;mf<2;++mf)
#pragma unroll
      for (int ks=0;ks<2;++ks){
        int r = w*32 + mf*16 + cl;
        int off = (ks*64 + gg*16) ^ ((r&7)<<4);
        af[mf][ks] = *(const short8*)((const char*)As + r*128 + off);
      }
#pragma unroll
    for (int nf=0;nf<BN/16;++nf){
      int r = nf*16 + cl;
      int rs = (r&7)<<4;
      short8 b0 = *(const short8*)((const char*)Bs + r*128 + ((gg*16) ^ rs));
      short8 b1 = *(const short8*)((const char*)Bs + r*128 + ((64 + gg*16) ^ rs));
      acc[0][nf] = MFMA_BF16(af[0][0], b0, acc[0][nf]);
      acc[0][nf] = MFMA_BF16(af[0][1], b1, acc[0][nf]);
      acc[1][nf] = MFMA_BF16(af[1][0], b0, acc[1][nf]);
      acc[1][nf] = MFMA_BF16(af[1][1], b1, acc[1][nf]);
    }
    __syncthreads();
  }

#pragma unroll
  for (int mf=0;mf<2;++mf)
#pragma unroll
    for (int nf=0;nf<BN/16;++nf){
      int row = mb + w*32 + mf*16 + gg*4;
      int col = nb + nf*16 + cl;
      if (OUTMODE==0){
        bf16* C = (bf16*)outp;
#pragma unroll
        for (int i=0;i<4;++i)
          C[((size_t)b*1024 + row+i)*512 + col] = __float2bfloat16(acc[mf][nf][i]*oscale);
      } else {
        float* C = (float*)outp;
#pragma unroll
        for (int i=0;i<4;++i)
          C[((size_t)b*1024 + row+i)*512 + col] = acc[mf][nf][i];
      }
    }
}

// ---------------- fused K+V projection (R8 single-buffered — proven) ----------------
__global__ __launch_bounds__(256)
void gemm_kv(const bf16* __restrict__ A,
             const bf16* __restrict__ wkt, const bf16* __restrict__ wvt,
             const int* __restrict__ sel,
             bf16* __restrict__ Kb, bf16* __restrict__ Vt){
  int b = blockIdx.z;
  int se = sel[b];
  int NK = se==0?512:(se==1?256:64);
  int nb = blockIdx.y*64;
  if (nb >= NK) return;
  int roff = se==0?0:(se==1?512:768);
  int mb = blockIdx.x*128;
  __shared__ __align__(16) bf16 As[128*64];
  __shared__ __align__(16) bf16 Bk[64*64];
  __shared__ __align__(16) bf16 Bv[64*64];
  int t = threadIdx.x, lane = t&63, w = t>>6, gg = lane>>4, cl = lane&15;
  f32x4 accK[2][4] = {}, accV[2][4] = {};
  const bf16* Ab = A + ((size_t)b*1024 + mb)*512;
  const bf16* Wk = wkt + (size_t)(roff+nb)*512;
  const bf16* Wv = wvt + (size_t)(roff+nb)*512;

  for (int k0 = 0; k0 < 512; k0 += 64){
#pragma unroll
    for (int j=0;j<4;++j){
      int o = (j*256+t)*16;
      int r = o>>7;
      int gs = ((o>>4)&7) ^ (r&7);
      glds16(Ab + (size_t)r*512 + k0 + gs*8, (char*)As + o);
    }
#pragma unroll
    for (int j=0;j<2;++j){
      int o = (j*256+t)*16;
      int r = o>>7;
      int gs = ((o>>4)&7) ^ (r&7);
      glds16(Wk + (size_t)r*512 + k0 + gs*8, (char*)Bk + o);
      glds16(Wv + (size_t)r*512 + k0 + gs*8, (char*)Bv + o);
    }
    __syncthreads();

    short8 af[2][2];
#pragma unroll
    for (int mf=0;mf<2;++mf)
#pragma unroll
      for (int ks=0;ks<2;++ks){
        int r = w*32 + mf*16 + cl;
        int off = (ks*64 + gg*16) ^ ((r&7)<<4);
        af[mf][ks] = *(const short8*)((const char*)As + r*128 + off);
      }
#pragma unroll
    for (int nf=0;nf<4;++nf){
      int r = nf*16 + cl;
      int rs = (r&7)<<4;
      short8 bk0 = *(const short8*)((const char*)Bk + r*128 + ((gg*16) ^ rs));
      short8 bk1 = *(const short8*)((const char*)Bk + r*128 + ((64 + gg*16) ^ rs));
      short8 bv0 = *(const short8*)((const char*)Bv + r*128 + ((gg*16) ^ rs));
      short8 bv1 = *(const short8*)((const char*)Bv + r*128 + ((64 + gg*16) ^ rs));
      accK[0][nf] = MFMA_BF16(af[0][0], bk0, accK[0][nf]);
      accK[0][nf] = MFMA_BF16(af[0][1], bk1, accK[0][nf]);
      accK[1][nf] = MFMA_BF16(af[1][0], bk0, accK[1][nf]);
      accK[1][nf] = MFMA_BF16(af[1][1], bk1, accK[1][nf]);
      accV[0][nf] = MFMA_BF16(af[0][0], bv0, accV[0][nf]);
      accV[0][nf] = MFMA_BF16(af[0][1], bv1, accV[0][nf]);
      accV[1][nf] = MFMA_BF16(af[1][0], bv0, accV[1][nf]);
      accV[1][nf] = MFMA_BF16(af[1][1], bv1, accV[1][nf]);
    }
    __syncthreads();
  }

#pragma unroll
  for (int mf=0;mf<2;++mf)
#pragma unroll
    for (int nf=0;nf<4;++nf){
      int row = mb + w*32 + mf*16 + gg*4;
      int col = nb + nf*16 + cl;
#pragma unroll
      for (int i=0;i<4;++i)
        Kb[((size_t)b*1024 + row+i)*512 + col] = __float2bfloat16(accK[mf][nf][i]);
      union { unsigned short u[4]; uint2 v; } pk;
#pragma unroll
      for (int i=0;i<4;++i) pk.u[i] = bfbits(accV[mf][nf][i]);
      *(uint2*)(Vt + ((size_t)b*512 + col)*1024 + row) = pk.v;
    }
}

// ---------------- MFMA flash attention (R8-proven math/geometry; 1D grid + XCD-chunked decode) ----
// 4096 blocks, 256 thr = 4 waves; wave w owns q-rows [w*32, w*32+32) of q-tile q0.
// Decode o=(n&7)*512+(n>>3) is bijective: XCD k (dispatch round-robin n%8) gets a contiguous
// range of 8 b's -> all 64 blocks sharing a batch's K/V panels (<=2MB, L2-fit) co-located.
__global__ __launch_bounds__(256, 4)
void attn_mfma(const bf16* __restrict__ Q, const bf16* __restrict__ K,
               const bf16* __restrict__ Vt, const int* __restrict__ sel,
               bf16* __restrict__ AO){
  int n = blockIdx.x;
  int o = (n&7)*512 + (n>>3);           // bijective XCD-chunk swizzle
  int q0 = (o&7)*128;
  int h  = (o>>3)&7;
  int b  = o>>6;
  int se = sel[b];
  int nkv = se==0?8:(se==1?4:1);
  int kvh = h/(8/nkv);
  __shared__ __align__(16) bf16 Ks[2][64*64];
  __shared__ __align__(16) bf16 Vs[2][64*64];
  int t = threadIdx.x, l = t&63, w = t>>6, cl = l&31, hi = l>>5;
  const bf16* Kb = K + (size_t)b*1024*512 + (size_t)kvh*64;
  const bf16* Vb = Vt + ((size_t)b*512 + (size_t)kvh*64)*1024;
  const bf16* Qg = Q + ((size_t)b*1024 + q0 + w*32 + cl)*512 + h*64;

  short8 qf0 = *(const short8*)(Qg + hi*8);
  short8 qf1 = *(const short8*)(Qg + 16 + hi*8);
  short8 qf2 = *(const short8*)(Qg + 32 + hi*8);
  short8 qf3 = *(const short8*)(Qg + 48 + hi*8);

  f32x16 accO0 = {}, accO1 = {};
  float lrow = 0.f;
  int swz = (cl&7)<<4;

#define STAGE(CUR, S0) { \
  _Pragma("unroll") for (int j=0;j<2;++j){ \
    int o2 = (j*256+t)*16; int r = o2>>7; int gs = ((o2>>4)&7)^(r&7); \
    glds16(Kb + (size_t)((S0)+r)*512 + gs*8, (char*)Ks[CUR] + o2); \
    glds16(Vb + (size_t)r*1024 + (S0) + gs*8, (char*)Vs[CUR] + o2); \
  } }

  STAGE(0, 0)
  __syncthreads();
  int cur = 0;
  for (int kt=0; kt<16; ++kt){
    if (kt<15) STAGE(cur^1, (kt+1)*64)

    const char* Kt_ = (const char*)Ks[cur];
    const char* Vt_ = (const char*)Vs[cur];

    f32x16 sc0 = {}, sc1 = {};
    __builtin_amdgcn_s_setprio(1);
#pragma unroll
    for (int ks=0;ks<4;++ks){
      int off = (ks*32 + hi*16) ^ swz;
      short8 kf0 = *(const short8*)(Kt_ + (size_t)cl*128 + off);
      short8 kf1 = *(const short8*)(Kt_ + (size_t)(32+cl)*128 + off);
      short8 qq = ks==0?qf0:(ks==1?qf1:(ks==2?qf2:qf3));
      sc0 = MFMA32(kf0, qq, sc0);
      sc1 = MFMA32(kf1, qq, sc1);
    }
    __builtin_amdgcn_s_setprio(0);

    float ts0=0.f, ts1=0.f, ts2=0.f, ts3=0.f;
#pragma unroll
    for (int r=0;r<16;r+=2){
      float a0 = EXPFN(sc0[r]);   float a1 = EXPFN(sc0[r+1]);
      float a2 = EXPFN(sc1[r]);   float a3 = EXPFN(sc1[r+1]);
      sc0[r]=a0; sc0[r+1]=a1; sc1[r]=a2; sc1[r+1]=a3;
      ts0+=a0; ts1+=a1; ts2+=a2; ts3+=a3;
    }
    lrow += (ts0+ts1)+(ts2+ts3);

    unsigned pA0[4],pB0[4],pA1[4],pB1[4];
#pragma unroll
    for (int m=0;m<4;++m){
      pA0[m]=packbf(sc0[4*m+0],sc0[4*m+1]); pB0[m]=packbf(sc0[4*m+2],sc0[4*m+3]);
      pA1[m]=packbf(sc1[4*m+0],sc1[4*m+1]); pB1[m]=packbf(sc1[4*m+2],sc1[4*m+3]);
    }
    unsigned rA0[2],rB0[2],rA1[2],rB1[2];
#pragma unroll
    for (int f=0;f<2;++f){
      rA0[f] = __shfl_xor(hi ? pA0[2*f] : pA0[2*f+1], 32);
      rB0[f] = __shfl_xor(hi ? pB0[2*f] : pB0[2*f+1], 32);
      rA1[f] = __shfl_xor(hi ? pA1[2*f] : pA1[2*f+1], 32);
      rB1[f] = __shfl_xor(hi ? pB1[2*f] : pB1[2*f+1], 32);
    }
    short8 pF[4];
#pragma unroll
    for (int f=0;f<2;++f){
      uint4 u;
      u.x = hi ? rA0[f]     : pA0[2*f];
      u.y = hi ? rB0[f]     : pB0[2*f];
      u.z = hi ? pA0[2*f+1] : rA0[f];
      u.w = hi ? pB0[2*f+1] : rB0[f];
      pF[f] = __builtin_bit_cast(short8, u);
      uint4 v;
      v.x = hi ? rA1[f]     : pA1[2*f];
      v.y = hi ? rB1[f]     : pB1[2*f];
      v.z = hi ? pA1[2*f+1] : rA1[f];
      v.w = hi ? pB1[2*f+1] : rB1[f];
      pF[2+f] = __builtin_bit_cast(short8, v);
    }

    __builtin_amdgcn_s_setprio(1);
#pragma unroll
    for (int ks2=0;ks2<4;++ks2){
      int off = (ks2*32 + hi*16) ^ swz;
      short8 vf0 = *(const short8*)(Vt_ + (size_t)cl*128 + off);
      short8 vf1 = *(const short8*)(Vt_ + (size_t)(32+cl)*128 + off);
      accO0 = MFMA32(vf0, pF[ks2], accO0);
      accO1 = MFMA32(vf1, pF[ks2], accO1);
    }
    __builtin_amdgcn_s_setprio(0);
    __syncthreads();
    cur ^= 1;
  }
#undef STAGE

  float lfull = lrow + __shfl_xor(lrow, 32);
  float inv = 1.f/lfull;
  int row = q0 + w*32 + cl;
  bf16* Ao = AO + ((size_t)b*1024 + row)*512 + h*64;
#pragma unroll
  for (int u=0;u<4;++u){
    union{ unsigned short s[4]; uint2 v; } P0, P1;
#pragma unroll
    for (int j2=0;j2<4;++j2){
      P0.s[j2] = bfbits(accO0[4*u+j2]*inv);
      P1.s[j2] = bfbits(accO1[4*u+j2]*inv);
    }
    *(uint2*)(Ao + 8*u + 4*hi) = P0.v;
    *(uint2*)(Ao + 32 + 8*u + 4*hi) = P1.v;
  }
}

extern "C" void kernel_launch(void* const* d_in, const int* in_sizes, int n_in,
                              void* d_out, int out_size, void* d_ws, size_t ws_size,
                              hipStream_t stream){
  const float* x    = (const float*)d_in[0];
  const float* r_w1 = (const float*)d_in[1];
  const float* r_b1 = (const float*)d_in[2];
  const float* r_w2 = (const float*)d_in[3];
  const float* r_b2 = (const float*)d_in[4];
  const float* wq[3] = {(const float*)d_in[5], (const float*)d_in[9],  (const float*)d_in[13]};
  const float* wk[3] = {(const float*)d_in[6], (const float*)d_in[10], (const float*)d_in[14]};
  const float* wv[3] = {(const float*)d_in[7], (const float*)d_in[11], (const float*)d_in[15]};
  const float* wo[3] = {(const float*)d_in[8], (const float*)d_in[12], (const float*)d_in[16]};

  // ws layout (4MiB header + 4*64MiB = 260MiB, proven footprint):
  char* ws = (char*)d_ws;
  int*   sel      = (int*)ws;
  float* partials = (float*)(ws + 4096);
  bf16*  wqt      = (bf16*)(ws + 4096);
  bf16*  wkt      = (bf16*)(ws + 4096 + 1572864);
  bf16*  wvt      = (bf16*)(ws + 4096 + 1572864 + 851968);
  bf16*  wot      = wqt;                         // O weights reuse Q region (after Q-GEMM)
  const size_t NE = (size_t)64*1024*512;
  bf16* xb = (bf16*)(ws + ((size_t)4<<20));
  bf16* Qb = xb + NE;
  bf16* Kb = Qb + NE;
  bf16* Vt = Kb + NE;
  bf16* AO = xb;                                 // alias: xb dead before attention writes

  xconv_mean<<<dim3(64,16), 256, 0, stream>>>(x, xb, partials);
  router_fused<<<64, 256, 0, stream>>>(partials, r_w1, r_b1, r_w2, r_b2, sel);

  wconv_qkv<<<dim3(8,8,9), 256, 0, stream>>>(wq[0],wq[1],wq[2], wk[0],wk[1],wk[2],
                                             wv[0],wv[1],wv[2], wqt, wkt, wvt);

  // Q projection (scores scale folded into Q), 128x128 tile (R8 config)
  gemm_mfma<0,128><<<dim3(8,4,64), 256, 0, stream>>>(
      xb, wqt, wqt + (size_t)512*512, wqt + (size_t)2*512*512,
      512,512,512, sel, (float)QSCALE, Qb);

  // fused K+V projection (shared A-tiles), 128x64 tile (R8 config)
  gemm_kv<<<dim3(8,8,64), 256, 0, stream>>>(xb, wkt, wvt, sel, Kb, Vt);

  // O weight transpose into the (now dead) Q weight buffer
  wconv_o<<<dim3(8,8,3), 256, 0, stream>>>(wo[0],wo[1],wo[2], wot);

  // attention: 1D grid, XCD-chunked decode (R8 math, scheduling-only change)
  attn_mfma<<<4096, 256, 0, stream>>>(Qb, Kb, Vt, sel, AO);

  // O projection (fp32 out), 128x128 tile (R8 config)
  gemm_mfma<2,128><<<dim3(8,4,64), 256, 0, stream>>>(
      AO, wot, wot + (size_t)512*512, wot + (size_t)2*512*512,
      512,512,512, sel, 1.0f, (float*)d_out);
}